// Round 2
// baseline (78805.078 us; speedup 1.0000x reference)
//
#include <hip/hip_runtime.h>

#define N_PTS 32768
#define K_CB  8192
#define D_DIM 256
#define BETA  0.5f

typedef _Float16 f16;
typedef __attribute__((ext_vector_type(8))) _Float16 f16x8;
typedef __attribute__((ext_vector_type(16))) float f32x16;

#define MARGIN  0.015f
#define CAP     32
#define POOLCAP (1u << 20)

// ---------------- new-path ws layout (byte offsets) ----------------
#define OFF_CB    ((size_t)0)                    // 8192*256 f32   = 8 MB
#define OFF_CH    (OFF_CB   + (size_t)K_CB*D_DIM*4)       // f16 codebook  = 4 MB
#define OFF_ZH    (OFF_CH   + (size_t)K_CB*D_DIM*2)       // f16 z         = 16 MB
#define OFF_CC    (OFF_ZH   + (size_t)N_PTS*D_DIM*2)      // ||c||^2       = 32 KB
#define OFF_ZZ    (OFF_CC   + (size_t)K_CB*4)             // ||z||^2       = 128 KB
#define OFF_CAND  (OFF_ZZ   + (size_t)N_PTS*4)            // u16[N][4][CAP]= 8 MB
#define OFF_CNT   (OFF_CAND + (size_t)N_PTS*4*CAP*2)      // u32[N][4]     = 512 KB
#define OFF_BEST  (OFF_CNT  + (size_t)N_PTS*4*4)          // u64[N]        = 256 KB
#define OFF_POOL  (OFF_BEST + (size_t)N_PTS*8)            // u32[POOLCAP]  = 4 MB
#define OFF_PCNT  (OFF_POOL + (size_t)POOLCAP*4)
#define OFF_ACC   (OFF_PCNT + 16)
#define WS_NEED   (OFF_ACC + 64)

// ---------------- fallback (round-1) ws layout, float offsets ----------------
#define F_CB_OFF   0
#define F_CC_OFF   (K_CB * D_DIM)
#define F_ZZ_OFF   (F_CC_OFF + K_CB)
#define F_IDX_OFF  (F_ZZ_OFF + N_PTS)
#define F_ACC_BYTE ((size_t)(F_IDX_OFF + N_PTS) * 4)

// ---------------------------------------------------------------------------
// codebook[k][d] = sum_j emb[k][j]*W[d][j] + b[d];  cc[k]=||c_k||^2; ch = f16(cb)
// Sequential-j fma chain (bit-exact vs reference per round-1 absmax=0.0).
// ---------------------------------------------------------------------------
__global__ __launch_bounds__(256) void k_codebook(
    const float* __restrict__ emb, const float* __restrict__ w,
    const float* __restrict__ b, float* __restrict__ cb, float* __restrict__ cc,
    f16* __restrict__ ch) {
  __shared__ float es[D_DIM];
  __shared__ float row[D_DIM];
  const int k = blockIdx.x;
  const int d = threadIdx.x;
  es[d] = emb[k * D_DIM + d];
  __syncthreads();
  const float* wr = w + d * D_DIM;
  float a = 0.f;
#pragma unroll 8
  for (int q = 0; q < D_DIM / 4; ++q) {
    float4 wv = *(const float4*)&wr[q * 4];
    a = fmaf(es[q * 4 + 0], wv.x, a);
    a = fmaf(es[q * 4 + 1], wv.y, a);
    a = fmaf(es[q * 4 + 2], wv.z, a);
    a = fmaf(es[q * 4 + 3], wv.w, a);
  }
  a += b[d];
  cb[k * D_DIM + d] = a;
  if (ch) ch[(size_t)k * D_DIM + d] = (f16)a;
  row[d] = a;
  __syncthreads();
  float s = 0.f;
#pragma unroll 8
  for (int j = 0; j < D_DIM; ++j) s = fmaf(row[j], row[j], s);
  if (d == 0) cc[k] = s;
}

__global__ __launch_bounds__(256) void k_zz(const float* __restrict__ z,
                                            float* __restrict__ zz) {
  const int n = blockIdx.x * 256 + threadIdx.x;
  const float* zr = z + (size_t)n * D_DIM;
  float s = 0.f;
#pragma unroll 8
  for (int q = 0; q < D_DIM / 4; ++q) {
    float4 v = *(const float4*)&zr[q * 4];
    s = fmaf(v.x, v.x, s);
    s = fmaf(v.y, v.y, s);
    s = fmaf(v.z, v.z, s);
    s = fmaf(v.w, v.w, s);
  }
  zz[n] = s;
}

__global__ __launch_bounds__(256) void k_zh(const float* __restrict__ z,
                                            f16* __restrict__ zh) {
  const size_t i = (size_t)blockIdx.x * 256 + threadIdx.x;  // 8 elems/thread
  const float4* zp = (const float4*)(z + i * 8);
  float4 a = zp[0], b = zp[1];
  f16x8 o = {(f16)a.x, (f16)a.y, (f16)a.z, (f16)a.w,
             (f16)b.x, (f16)b.y, (f16)b.z, (f16)b.w};
  *(f16x8*)(zh + i * 8) = o;
}

// ---------------------------------------------------------------------------
// k_main: f16-MFMA distance pass + candidate flagging.
// Grid 512 = 128 row-blocks x 4 code-quarters. Block: 8 waves x 32 z-rows.
// Wave: z frags resident in regs (B operand, lane axis = z-row l&31);
// codebook tile (32 codes x 256 depth, f16) double-buffered in LDS with
// XOR-swizzle (slot ^= code&7) -> conflict-free ds_read_b128 A-frags.
// ---------------------------------------------------------------------------
__global__ __launch_bounds__(512, 4) void k_main(
    const f16* __restrict__ zh, const f16* __restrict__ ch,
    const float* __restrict__ zz, const float* __restrict__ cc,
    unsigned int* __restrict__ cntG, unsigned short* __restrict__ candG,
    unsigned int* __restrict__ pool, unsigned int* __restrict__ poolcnt) {
  __shared__ __align__(16) char chs[2][16384];
  __shared__ unsigned short candL[256 * CAP];
  __shared__ unsigned int cntL[256];

  const int tid = threadIdx.x;
  const int w = tid >> 6, l = tid & 63;
  const int lc = l & 31, h = l >> 5;
  const int rb = blockIdx.x >> 2, q = blockIdx.x & 3;
  const int n0 = rb * 256;
  const int lrow = w * 32 + lc;
  const int row = n0 + lrow;
  const int code0 = q * 2048;

  for (int i = tid; i < 256; i += 512) cntL[i] = 0;

  // resident z fragments: zh[row][kc*16 + h*8 .. +7]
  const f16x8* zv = (const f16x8*)zh;
  f16x8 zf[16];
#pragma unroll
  for (int kc = 0; kc < 16; ++kc) zf[kc] = zv[(size_t)row * 32 + kc * 2 + h];

  const float zzv = zz[row];
  float runmin = 3.4e38f;

  // staging: tile = 1024 16B-slots; slot m: code=m>>5, s=m&31; src slot s^(code&7)
  const f16x8* cv = (const f16x8*)ch;
  const int m0 = tid, m1 = tid + 512;
  const int cl0 = m0 >> 5, s0 = (m0 & 31) ^ (cl0 & 7);
  const int cl1 = m1 >> 5, s1 = (m1 & 31) ^ (cl1 & 7);
  const size_t base0 = (size_t)(code0 + cl0) * 32 + s0;
  const size_t base1 = (size_t)(code0 + cl1) * 32 + s1;

  {  // prologue: tile 0 -> buf 0
    f16x8 a = cv[base0], b = cv[base1];
    *(f16x8*)(chs[0] + m0 * 16) = a;
    *(f16x8*)(chs[0] + m1 * 16) = b;
  }
  __syncthreads();

  const float4* ccv4 = (const float4*)cc;
  int buf = 0;
  for (int t = 0; t < 64; ++t) {
    f16x8 nx0, nx1;
    if (t < 63) {  // issue next-tile loads early (hide under MFMA)
      nx0 = cv[base0 + (size_t)(t + 1) * 1024];
      nx1 = cv[base1 + (size_t)(t + 1) * 1024];
    }
    f32x16 acc = {0.f, 0.f, 0.f, 0.f, 0.f, 0.f, 0.f, 0.f,
                  0.f, 0.f, 0.f, 0.f, 0.f, 0.f, 0.f, 0.f};
    const char* cbase = chs[buf] + lc * 512;
#pragma unroll
    for (int kc = 0; kc < 16; ++kc) {
      f16x8 af = *(const f16x8*)(cbase + (((kc * 2 + h) ^ (lc & 7)) << 4));
      acc = __builtin_amdgcn_mfma_f32_32x32x16_f16(af, zf[kc], acc, 0, 0, 0);
    }
    // epilogue: d~ = zz + cc - 2*dot ; per-lane min over 16 codes
    const int tb = code0 + t * 32;
    float dls[16];
    float dmin = 3.4e38f;
#pragma unroll
    for (int r4 = 0; r4 < 4; ++r4) {
      float4 c4 = ccv4[(tb + 8 * r4 + 4 * h) >> 2];
      float d0 = fmaf(-2.f, acc[r4 * 4 + 0], zzv + c4.x);
      float d1 = fmaf(-2.f, acc[r4 * 4 + 1], zzv + c4.y);
      float d2 = fmaf(-2.f, acc[r4 * 4 + 2], zzv + c4.z);
      float d3 = fmaf(-2.f, acc[r4 * 4 + 3], zzv + c4.w);
      dls[r4 * 4 + 0] = d0; dls[r4 * 4 + 1] = d1;
      dls[r4 * 4 + 2] = d2; dls[r4 * 4 + 3] = d3;
      dmin = fminf(dmin, fminf(fminf(d0, d1), fminf(d2, d3)));
    }
    dmin = fminf(dmin, __shfl_xor(dmin, 32));  // merge lane pair (same z-row)
    runmin = fminf(runmin, dmin);
    const float thr = runmin + MARGIN;
#pragma unroll
    for (int r = 0; r < 16; ++r) {
      if (dls[r] < thr) {
        int code = tb + 8 * (r >> 2) + 4 * h + (r & 3);
        unsigned int p = atomicAdd(&cntL[lrow], 1u);
        if (p < CAP) candL[lrow * CAP + p] = (unsigned short)code;
        else {
          unsigned int g = atomicAdd(poolcnt, 1u);
          if (g < POOLCAP) pool[g] = ((unsigned int)row << 13) | (unsigned int)code;
        }
      }
    }
    if (t < 63) {  // land staged tile into other buffer
      *(f16x8*)(chs[buf ^ 1] + m0 * 16) = nx0;
      *(f16x8*)(chs[buf ^ 1] + m1 * 16) = nx1;
    }
    __syncthreads();
    buf ^= 1;
  }

  // writeout lists
  unsigned int pc = *poolcnt;
  for (int r = tid; r < 256; r += 512) {
    unsigned int c = cntL[r];
    unsigned int cw = c;
    if (c > CAP) cw = (pc >= POOLCAP) ? 0xFFFFu : CAP;
    cntG[((size_t)(n0 + r)) * 4 + q] = cw;
    unsigned int nc = (cw == 0xFFFFu) ? 0u : cw;
    for (unsigned int j = 0; j < nc; ++j)
      candG[(((size_t)(n0 + r)) * 4 + q) * CAP + j] = candL[r * CAP + j];
  }
}

// exact fp32 distance, bit-replicating round-1 formula
__device__ inline unsigned long long exact_key(const float4* __restrict__ zr,
                                               const float* __restrict__ cb,
                                               float zzn, const float* __restrict__ cc,
                                               int code) {
  float acc = 0.f;
  const float4* cr = (const float4*)&cb[(size_t)code * D_DIM];
#pragma unroll 8
  for (int u = 0; u < D_DIM / 4; ++u) {
    float4 c4 = cr[u], z4 = zr[u];
    acc = fmaf(z4.x, c4.x, acc);
    acc = fmaf(z4.y, c4.y, acc);
    acc = fmaf(z4.z, c4.z, acc);
    acc = fmaf(z4.w, c4.w, acc);
  }
  float t = zzn + cc[code];
  float dd = fmaf(-2.f, acc, t);
  return (((unsigned long long)__float_as_uint(dd)) << 32) | (unsigned int)code;
}

__global__ __launch_bounds__(256) void k_refine(
    const float* __restrict__ z, const float* __restrict__ cb,
    const float* __restrict__ zz, const float* __restrict__ cc,
    const unsigned int* __restrict__ cntG, const unsigned short* __restrict__ candG,
    unsigned long long* __restrict__ best) {
  __shared__ float zls[4][D_DIM];
  const int tid = threadIdx.x;
  const int v = tid >> 6, l = tid & 63;
  const int n = blockIdx.x * 4 + v;
  *(float4*)&zls[v][l * 4] = *(const float4*)&z[(size_t)n * D_DIM + l * 4];
  __syncthreads();

  unsigned int c0 = cntG[(size_t)n * 4 + 0], c1 = cntG[(size_t)n * 4 + 1];
  unsigned int c2 = cntG[(size_t)n * 4 + 2], c3 = cntG[(size_t)n * 4 + 3];
  const bool full = (c0 == 0xFFFFu) | (c1 == 0xFFFFu) | (c2 == 0xFFFFu) | (c3 == 0xFFFFu);
  const float zzn = zz[n];
  const float4* zr = (const float4*)zls[v];
  unsigned long long key = ~0ull;

  if (!full) {
    if (c0 > CAP) c0 = CAP; if (c1 > CAP) c1 = CAP;
    if (c2 > CAP) c2 = CAP; if (c3 > CAP) c3 = CAP;
    const unsigned int o1 = c0, o2 = c0 + c1, o3 = o2 + c2, tot = o3 + c3;
    for (unsigned int ci = l; ci < tot; ci += 64) {
      int qq, j;
      if (ci >= o3)      { qq = 3; j = ci - o3; }
      else if (ci >= o2) { qq = 2; j = ci - o2; }
      else if (ci >= o1) { qq = 1; j = ci - o1; }
      else               { qq = 0; j = ci; }
      int code = candG[((size_t)n * 4 + qq) * CAP + j];
      unsigned long long k2 = exact_key(zr, cb, zzn, cc, code);
      key = key < k2 ? key : k2;
    }
  } else {  // sentinel: exact full scan for this row
    for (int code = l; code < K_CB; code += 64) {
      unsigned long long k2 = exact_key(zr, cb, zzn, cc, code);
      key = key < k2 ? key : k2;
    }
  }
#pragma unroll
  for (int off = 1; off < 64; off <<= 1) {
    unsigned long long o = __shfl_xor(key, off);
    key = key < o ? key : o;
  }
  if (l == 0) atomicMin(&best[n], key);
}

__global__ void k_pool(const float* __restrict__ z, const float* __restrict__ cb,
                       const float* __restrict__ zz, const float* __restrict__ cc,
                       const unsigned int* __restrict__ pool,
                       const unsigned int* __restrict__ poolcnt,
                       unsigned long long* __restrict__ best) {
  unsigned int pc = *poolcnt;
  if (pc > POOLCAP) pc = POOLCAP;
  for (unsigned int i = blockIdx.x * 256 + threadIdx.x; i < pc; i += gridDim.x * 256) {
    unsigned int e = pool[i];
    int n = e >> 13, code = e & 8191;
    unsigned long long k2 =
        exact_key((const float4*)&z[(size_t)n * D_DIM], cb, zz[n], cc, code);
    atomicMin(&best[n], k2);
  }
}

// ---------------------------------------------------------------------------
// round-1 exact argmin kernel, kept as fallback when ws is small
// ---------------------------------------------------------------------------
#define BN  64
#define BKC 128
#define DC  32
#define LDP (DC + 4)
__global__ __launch_bounds__(256) void k_argmin(
    const float* __restrict__ z, const float* __restrict__ cb,
    const float* __restrict__ zz, const float* __restrict__ cc,
    int* __restrict__ out_idx) {
  __shared__ float zs[BN][LDP];
  __shared__ float cs[BKC][LDP];
  __shared__ float red_d[BN][16];
  __shared__ int   red_k[BN][16];
  const int tid = threadIdx.x;
  const int tn = tid & 15, tk = tid >> 4;
  const int n0 = blockIdx.x * BN;
  float zzv[4];
#pragma unroll
  for (int i = 0; i < 4; ++i) zzv[i] = zz[n0 + tn + 16 * i];
  float best[4]; int bidx[4];
#pragma unroll
  for (int i = 0; i < 4; ++i) { best[i] = 3.4e38f; bidx[i] = 0; }
  for (int kt = 0; kt < K_CB / BKC; ++kt) {
    float acc[4][8];
#pragma unroll
    for (int i = 0; i < 4; ++i)
#pragma unroll
      for (int j = 0; j < 8; ++j) acc[i][j] = 0.f;
    for (int ch = 0; ch < D_DIM / DC; ++ch) {
      __syncthreads();
#pragma unroll
      for (int s = 0; s < 2; ++s) {
        int f = tid + 256 * s, r = f >> 3, c4 = f & 7;
        *(float4*)&zs[r][c4 * 4] =
            *(const float4*)&z[(size_t)(n0 + r) * D_DIM + ch * DC + c4 * 4];
      }
#pragma unroll
      for (int s = 0; s < 4; ++s) {
        int f = tid + 256 * s, r = f >> 3, c4 = f & 7;
        *(float4*)&cs[r][c4 * 4] =
            *(const float4*)&cb[(size_t)(kt * BKC + r) * D_DIM + ch * DC + c4 * 4];
      }
      __syncthreads();
#pragma unroll
      for (int qq = 0; qq < DC / 4; ++qq) {
        float4 zr[4], cr[8];
#pragma unroll
        for (int i = 0; i < 4; ++i) zr[i] = *(const float4*)&zs[tn + 16 * i][4 * qq];
#pragma unroll
        for (int j = 0; j < 8; ++j) cr[j] = *(const float4*)&cs[tk + 16 * j][4 * qq];
#pragma unroll
        for (int i = 0; i < 4; ++i)
#pragma unroll
          for (int j = 0; j < 8; ++j) {
            acc[i][j] = fmaf(zr[i].x, cr[j].x, acc[i][j]);
            acc[i][j] = fmaf(zr[i].y, cr[j].y, acc[i][j]);
            acc[i][j] = fmaf(zr[i].z, cr[j].z, acc[i][j]);
            acc[i][j] = fmaf(zr[i].w, cr[j].w, acc[i][j]);
          }
      }
    }
#pragma unroll
    for (int j = 0; j < 8; ++j) {
      const int k = kt * BKC + tk + 16 * j;
      const float cck = cc[k];
#pragma unroll
      for (int i = 0; i < 4; ++i) {
        float t = zzv[i] + cck;
        float dd = fmaf(-2.f, acc[i][j], t);
        if (dd < best[i]) { best[i] = dd; bidx[i] = k; }
      }
    }
  }
#pragma unroll
  for (int i = 0; i < 4; ++i) {
    red_d[tn + 16 * i][tk] = best[i];
    red_k[tn + 16 * i][tk] = bidx[i];
  }
  __syncthreads();
  if (tid < BN) {
    float bd = red_d[tid][0]; int bk = red_k[tid][0];
#pragma unroll
    for (int t2 = 1; t2 < 16; ++t2) {
      float dd = red_d[tid][t2]; int kk = red_k[tid][t2];
      if (dd < bd || (dd == bd && kk < bk)) { bd = dd; bk = kk; }
    }
    out_idx[n0 + tid] = bk;
  }
}

// ---------------------------------------------------------------------------
// gather + straight-through out + loss partials (two index sources)
// ---------------------------------------------------------------------------
template <int MODE>
__global__ __launch_bounds__(256) void k_gather(
    const float* __restrict__ z, const float* __restrict__ cb,
    const void* __restrict__ idx_src, float* __restrict__ out,
    double* __restrict__ accum) {
  const int tid = threadIdx.x;
  const int lane = tid & 63, wv = tid >> 6;
  const int base = blockIdx.x * 64 + wv * 16;
  double lsum = 0.0;
  for (int r = 0; r < 16; ++r) {
    const int n = base + r;
    int k;
    if (MODE == 0) k = ((const int*)idx_src)[n];
    else k = (int)(((const unsigned long long*)idx_src)[n] & 8191ull);
    float4 c4 = *(const float4*)&cb[(size_t)k * D_DIM + lane * 4];
    float4 z4 = *(const float4*)&z[(size_t)n * D_DIM + lane * 4];
    float e0 = c4.x - z4.x, e1 = c4.y - z4.y, e2 = c4.z - z4.z, e3 = c4.w - z4.w;
    lsum += (double)e0 * e0 + (double)e1 * e1 + (double)e2 * e2 + (double)e3 * e3;
    float4 o;
    o.x = z4.x + e0; o.y = z4.y + e1; o.z = z4.z + e2; o.w = z4.w + e3;
    *(float4*)&out[(size_t)n * D_DIM + lane * 4] = o;
    if (lane == 0) out[(size_t)N_PTS * D_DIM + n] = (float)k;
  }
#pragma unroll
  for (int off = 32; off > 0; off >>= 1) lsum += __shfl_down(lsum, off);
  __shared__ double wsum[4];
  if (lane == 0) wsum[wv] = lsum;
  __syncthreads();
  if (tid == 0) atomicAdd(accum, wsum[0] + wsum[1] + wsum[2] + wsum[3]);
}

__global__ void k_loss(const double* __restrict__ accum, float* __restrict__ out) {
  float m = (float)(*accum / (double)((size_t)N_PTS * D_DIM));
  out[(size_t)N_PTS * D_DIM + N_PTS] = BETA * m + m;
}

extern "C" void kernel_launch(void* const* d_in, const int* in_sizes, int n_in,
                              void* d_out, int out_size, void* d_ws, size_t ws_size,
                              hipStream_t stream) {
  const float* z   = (const float*)d_in[0];
  const float* emb = (const float*)d_in[1];
  const float* w   = (const float*)d_in[2];
  const float* b   = (const float*)d_in[3];
  float* out = (float*)d_out;
  char* ws = (char*)d_ws;

  if (ws_size >= WS_NEED) {
    float* cb = (float*)(ws + OFF_CB);
    f16*   ch = (f16*)(ws + OFF_CH);
    f16*   zh = (f16*)(ws + OFF_ZH);
    float* cc = (float*)(ws + OFF_CC);
    float* zz = (float*)(ws + OFF_ZZ);
    unsigned short* candG = (unsigned short*)(ws + OFF_CAND);
    unsigned int*   cntG  = (unsigned int*)(ws + OFF_CNT);
    unsigned long long* best = (unsigned long long*)(ws + OFF_BEST);
    unsigned int* pool    = (unsigned int*)(ws + OFF_POOL);
    unsigned int* poolcnt = (unsigned int*)(ws + OFF_PCNT);
    double* accum         = (double*)(ws + OFF_ACC);

    hipMemsetAsync(best, 0xFF, (size_t)N_PTS * 8, stream);
    hipMemsetAsync(poolcnt, 0, 4, stream);
    hipMemsetAsync(accum, 0, 8, stream);

    k_codebook<<<K_CB, 256, 0, stream>>>(emb, w, b, cb, cc, ch);
    k_zz<<<N_PTS / 256, 256, 0, stream>>>(z, zz);
    k_zh<<<(N_PTS * D_DIM) / (8 * 256), 256, 0, stream>>>(z, zh);
    k_main<<<512, 512, 0, stream>>>(zh, ch, zz, cc, cntG, candG, pool, poolcnt);
    k_pool<<<256, 256, 0, stream>>>(z, cb, zz, cc, pool, poolcnt, best);
    k_refine<<<N_PTS / 4, 256, 0, stream>>>(z, cb, zz, cc, cntG, candG, best);
    k_gather<1><<<N_PTS / 64, 256, 0, stream>>>(z, cb, best, out, accum);
    k_loss<<<1, 1, 0, stream>>>(accum, out);
  } else {
    float* ws_f = (float*)d_ws;
    float* cb = ws_f + F_CB_OFF;
    float* cc = ws_f + F_CC_OFF;
    float* zz = ws_f + F_ZZ_OFF;
    int*   idx = (int*)(ws_f + F_IDX_OFF);
    double* accum = (double*)((char*)d_ws + F_ACC_BYTE);
    hipMemsetAsync(accum, 0, sizeof(double), stream);
    k_codebook<<<K_CB, 256, 0, stream>>>(emb, w, b, cb, cc, (f16*)nullptr);
    k_zz<<<N_PTS / 256, 256, 0, stream>>>(z, zz);
    k_argmin<<<N_PTS / BN, 256, 0, stream>>>(z, cb, zz, cc, idx);
    k_gather<0><<<N_PTS / 64, 256, 0, stream>>>(z, cb, idx, out, accum);
    k_loss<<<1, 1, 0, stream>>>(accum, out);
  }
}

// Round 4
// 649.939 us; speedup vs baseline: 121.2500x; 121.2500x over previous
//
#include <hip/hip_runtime.h>

#define N_PTS 32768
#define K_CB  8192
#define D_DIM 256
#define BETA  0.5f

typedef _Float16 f16;
typedef __attribute__((ext_vector_type(8))) _Float16 f16x8;
typedef __attribute__((ext_vector_type(16))) float f32x16;

#define MARGIN  2.5e-4f
#define CAPQ    32
#define DSCALE  4096.0f
#define INV2S   (-4.8828125e-4f)   // -2/4096, exact power of two

// ---------------- ws layout (byte offsets) ----------------
#define OFF_CB   ((size_t)0)                                  // f32 [K][D]   8 MB
#define OFF_DH   (OFF_CB   + (size_t)K_CB*D_DIM*4)            // f16 delta*4096 [K][D] 4 MB
#define OFF_UH   (OFF_DH   + (size_t)K_CB*D_DIM*2)            // f16 (z-b) [N][D] 16 MB
#define OFF_CC   (OFF_UH   + (size_t)N_PTS*D_DIM*2)           // f32 ||c||^2 [K]
#define OFF_ZZ   (OFF_CC   + (size_t)K_CB*4)                  // f32 ||z||^2 [N]
#define OFF_D2   (OFF_ZZ   + (size_t)N_PTS*4)                 // f32 ||delta||^2 [K]
#define OFF_CAND (OFF_D2   + (size_t)K_CB*4)                  // u16 [N][4][CAPQ] 8 MB
#define OFF_CNT  (OFF_CAND + (size_t)N_PTS*4*CAPQ*2)          // u32 [N][4]
#define OFF_BEST (OFF_CNT  + (size_t)N_PTS*4*4)               // u64 [N]
#define OFF_ACC  (OFF_BEST + (size_t)N_PTS*8)
#define WS_NEED  (OFF_ACC + 64)

// ---------------- fallback (round-1) ws layout, float offsets ----------------
#define F_CB_OFF   0
#define F_CC_OFF   (K_CB * D_DIM)
#define F_ZZ_OFF   (F_CC_OFF + K_CB)
#define F_IDX_OFF  (F_ZZ_OFF + N_PTS)
#define F_ACC_BYTE ((size_t)(F_IDX_OFF + N_PTS) * 4)

// ---------------------------------------------------------------------------
// codebook: cb[k][d] = seq-fma(emb_k, W_d) + b[d]  (bit-matches reference per r1)
// cc[k] = seq ||c||^2 (order-sensitive: used in exact refine formula)
// delta = cb - b (exact in fp32 here); dh = f16(delta*4096); dd2[k]=||delta||^2
// ---------------------------------------------------------------------------
__global__ __launch_bounds__(256) void k_codebook(
    const float* __restrict__ emb, const float* __restrict__ w,
    const float* __restrict__ bias, float* __restrict__ cb,
    float* __restrict__ cc, float* __restrict__ dd2, f16* __restrict__ dh) {
  __shared__ float es[D_DIM];
  __shared__ float row[D_DIM];
  __shared__ float rowd[D_DIM];
  const int k = blockIdx.x;
  const int d = threadIdx.x;
  es[d] = emb[k * D_DIM + d];
  __syncthreads();
  const float* wr = w + d * D_DIM;
  float a = 0.f;
#pragma unroll 8
  for (int q = 0; q < D_DIM / 4; ++q) {
    float4 wv = *(const float4*)&wr[q * 4];
    a = fmaf(es[q * 4 + 0], wv.x, a);
    a = fmaf(es[q * 4 + 1], wv.y, a);
    a = fmaf(es[q * 4 + 2], wv.z, a);
    a = fmaf(es[q * 4 + 3], wv.w, a);
  }
  const float bd = bias[d];
  a += bd;
  cb[k * D_DIM + d] = a;
  const float delta = a - bd;
  if (dh) dh[(size_t)k * D_DIM + d] = (f16)(delta * DSCALE);
  row[d] = a;
  rowd[d] = delta;
  __syncthreads();
  if (d == 0) {
    float s = 0.f;
#pragma unroll 8
    for (int j = 0; j < D_DIM; ++j) s = fmaf(row[j], row[j], s);
    cc[k] = s;
  } else if (d == 1 && dd2) {
    float s2 = 0.f;
#pragma unroll 8
    for (int j = 0; j < D_DIM; ++j) s2 = fmaf(rowd[j], rowd[j], s2);
    dd2[k] = s2;
  }
}

__global__ __launch_bounds__(256) void k_zz(const float* __restrict__ z,
                                            float* __restrict__ zz) {
  const int n = blockIdx.x * 256 + threadIdx.x;
  const float* zr = z + (size_t)n * D_DIM;
  float s = 0.f;
#pragma unroll 8
  for (int q = 0; q < D_DIM / 4; ++q) {
    float4 v = *(const float4*)&zr[q * 4];
    s = fmaf(v.x, v.x, s);
    s = fmaf(v.y, v.y, s);
    s = fmaf(v.z, v.z, s);
    s = fmaf(v.w, v.w, s);
  }
  zz[n] = s;
}

// uh[n][d] = f16(z[n][d] - b[d])
__global__ __launch_bounds__(256) void k_zu(const float* __restrict__ z,
                                            const float* __restrict__ bias,
                                            f16* __restrict__ uh) {
  const size_t i = (size_t)blockIdx.x * 256 + threadIdx.x;  // 8 elems/thread
  const int d0 = (int)((i * 8) & (D_DIM - 1));
  const float4* zp = (const float4*)(z + i * 8);
  float4 a = zp[0], c = zp[1];
  float4 b0 = *(const float4*)&bias[d0];
  float4 b1 = *(const float4*)&bias[d0 + 4];
  f16x8 o = {(f16)(a.x - b0.x), (f16)(a.y - b0.y), (f16)(a.z - b0.z), (f16)(a.w - b0.w),
             (f16)(c.x - b1.x), (f16)(c.y - b1.y), (f16)(c.z - b1.z), (f16)(c.w - b1.w)};
  *(f16x8*)(uh + i * 8) = o;
}

// ---------------------------------------------------------------------------
// k_main: centered f16-MFMA pass. s~(n,k) = -2 u.delta + ||delta||^2
// Grid 256 = 64 row-blocks x 4 code-quarters. Block 512 thr = 8 waves x 64 rows.
// Per wave: 2 resident u-fragment sets (rows lc / lc+32); codebook delta tiles
// (32 codes x 256 K f16 = 16 KB) double-buffered in LDS, XOR-swizzled
// (slot ^ (code&7)) so ds_read_b128 A-frags are conflict-free; each A-read
// feeds 2 MFMAs. Flag codes with s~ < runmin+MARGIN into per-row LDS lists.
// ---------------------------------------------------------------------------
__global__ __launch_bounds__(512, 2) void k_main(
    const f16* __restrict__ uh, const f16* __restrict__ dh,
    const float* __restrict__ dd2,
    unsigned int* __restrict__ cntG, unsigned short* __restrict__ candG) {
  __shared__ __align__(16) char tile[2][16384];
  __shared__ unsigned short candL[512][CAPQ];
  __shared__ unsigned int cntL[512];

  const int tid = threadIdx.x;
  const int w = tid >> 6, l = tid & 63;
  const int lc = l & 31, h = l >> 5;
  const int rb = blockIdx.x >> 2, q = blockIdx.x & 3;
  const int n0 = rb * 512;
  const int lrowA = w * 64 + lc;
  const int lrowB = lrowA + 32;
  const int rowA = n0 + lrowA, rowB = n0 + lrowB;
  const int code0 = q * 2048;

  cntL[tid] = 0;

  // resident u fragments: lane holds k = kc*16 + h*8 + j  (B-operand layout)
  const f16x8* uv = (const f16x8*)uh;
  f16x8 ua[16], ub[16];
#pragma unroll
  for (int kc = 0; kc < 16; ++kc) {
    ua[kc] = uv[(size_t)rowA * 32 + kc * 2 + h];
    ub[kc] = uv[(size_t)rowB * 32 + kc * 2 + h];
  }

  // staging: tile = 1024 16B-slots; slot m -> code m>>5, slot s=m&31;
  // pre-swizzled global source s^(code&7), linear LDS dest (m201 pattern)
  const f16x8* cv = (const f16x8*)dh;
  const int m0 = tid, m1 = tid + 512;
  const int cl0 = m0 >> 5, s0 = (m0 & 31) ^ (cl0 & 7);
  const int cl1 = m1 >> 5, s1 = (m1 & 31) ^ (cl1 & 7);
  const size_t base0 = (size_t)(code0 + cl0) * 32 + s0;
  const size_t base1 = (size_t)(code0 + cl1) * 32 + s1;

  {
    f16x8 a = cv[base0], b2 = cv[base1];
    *(f16x8*)(tile[0] + m0 * 16) = a;
    *(f16x8*)(tile[0] + m1 * 16) = b2;
  }
  __syncthreads();

  float runA = 3.4e38f, runB = 3.4e38f;
  const float4* d2v = (const float4*)dd2;
  int buf = 0;
  for (int t = 0; t < 64; ++t) {
    f16x8 nx0, nx1;
    if (t < 63) {  // issue next-tile loads early; land after MFMA
      nx0 = cv[base0 + (size_t)(t + 1) * 1024];
      nx1 = cv[base1 + (size_t)(t + 1) * 1024];
    }
    f32x16 accA = {0.f,0.f,0.f,0.f,0.f,0.f,0.f,0.f,0.f,0.f,0.f,0.f,0.f,0.f,0.f,0.f};
    f32x16 accB = {0.f,0.f,0.f,0.f,0.f,0.f,0.f,0.f,0.f,0.f,0.f,0.f,0.f,0.f,0.f,0.f};
    const char* cbase = tile[buf] + lc * 512;
#pragma unroll
    for (int kc = 0; kc < 16; ++kc) {
      f16x8 af = *(const f16x8*)(cbase + (((kc * 2 + h) ^ (lc & 7)) << 4));
      accA = __builtin_amdgcn_mfma_f32_32x32x16_f16(af, ua[kc], accA, 0, 0, 0);
      accB = __builtin_amdgcn_mfma_f32_32x32x16_f16(af, ub[kc], accB, 0, 0, 0);
    }

    // epilogue: s~ = fma(dot, -2^-11, dd2)   (dot = 4096 * u.delta)
    const int tb = code0 + t * 32;
    float sA[16], sB[16];
    float mA = 3.4e38f, mB = 3.4e38f;
#pragma unroll
    for (int r4 = 0; r4 < 4; ++r4) {
      float4 dq = d2v[(tb + 8 * r4 + 4 * h) >> 2];
      sA[4*r4+0] = fmaf(accA[4*r4+0], INV2S, dq.x);
      sA[4*r4+1] = fmaf(accA[4*r4+1], INV2S, dq.y);
      sA[4*r4+2] = fmaf(accA[4*r4+2], INV2S, dq.z);
      sA[4*r4+3] = fmaf(accA[4*r4+3], INV2S, dq.w);
      sB[4*r4+0] = fmaf(accB[4*r4+0], INV2S, dq.x);
      sB[4*r4+1] = fmaf(accB[4*r4+1], INV2S, dq.y);
      sB[4*r4+2] = fmaf(accB[4*r4+2], INV2S, dq.z);
      sB[4*r4+3] = fmaf(accB[4*r4+3], INV2S, dq.w);
      mA = fminf(mA, fminf(fminf(sA[4*r4+0], sA[4*r4+1]), fminf(sA[4*r4+2], sA[4*r4+3])));
      mB = fminf(mB, fminf(fminf(sB[4*r4+0], sB[4*r4+1]), fminf(sB[4*r4+2], sB[4*r4+3])));
    }
    // lanes l and l^32 hold the same rows (different code offsets) -> merge
    mA = fminf(mA, __shfl_xor(mA, 32));
    mB = fminf(mB, __shfl_xor(mB, 32));
    runA = fminf(runA, mA);
    runB = fminf(runB, mB);
    const float thA = runA + MARGIN, thB = runB + MARGIN;
#pragma unroll
    for (int r = 0; r < 16; ++r) {
      const int code = tb + 8 * (r >> 2) + 4 * h + (r & 3);
      if (sA[r] < thA) {
        unsigned int p = atomicAdd(&cntL[lrowA], 1u);
        if (p < CAPQ) candL[lrowA][p] = (unsigned short)code;
      }
      if (sB[r] < thB) {
        unsigned int p = atomicAdd(&cntL[lrowB], 1u);
        if (p < CAPQ) candL[lrowB][p] = (unsigned short)code;
      }
    }
    if (t < 63) {
      *(f16x8*)(tile[buf ^ 1] + m0 * 16) = nx0;
      *(f16x8*)(tile[buf ^ 1] + m1 * 16) = nx1;
    }
    __syncthreads();
    buf ^= 1;
  }

  // writeout: thread tid owns row n0+tid (written by its own wave)
  unsigned int c = cntL[tid];
  unsigned int cw = (c > CAPQ) ? 0xFFFFu : c;
  cntG[((size_t)(n0 + tid)) * 4 + q] = cw;
  unsigned int nc = (cw == 0xFFFFu) ? 0u : cw;
  for (unsigned int j = 0; j < nc; ++j)
    candG[(((size_t)(n0 + tid)) * 4 + q) * CAPQ + j] = candL[tid][j];
}

// exact fp32 distance, bit-replicating the round-1 (reference-matching) formula
__device__ inline unsigned long long exact_key(const float* __restrict__ zr,
                                               const float* __restrict__ cb,
                                               float zzn, const float* __restrict__ cc,
                                               int code) {
  float acc = 0.f;
  const float4* cr = (const float4*)&cb[(size_t)code * D_DIM];
  const float4* z4p = (const float4*)zr;
#pragma unroll 8
  for (int u = 0; u < D_DIM / 4; ++u) {
    float4 c4 = cr[u], z4 = z4p[u];
    acc = fmaf(z4.x, c4.x, acc);
    acc = fmaf(z4.y, c4.y, acc);
    acc = fmaf(z4.z, c4.z, acc);
    acc = fmaf(z4.w, c4.w, acc);
  }
  float t = zzn + cc[code];
  float dd = fmaf(-2.f, acc, t);
  return (((unsigned long long)__float_as_uint(dd)) << 32) | (unsigned int)code;
}

// one wave per row; refine candidate lists (or full-scan on sentinel)
__global__ __launch_bounds__(256) void k_refine(
    const float* __restrict__ z, const float* __restrict__ cb,
    const float* __restrict__ zz, const float* __restrict__ cc,
    const unsigned int* __restrict__ cntG, const unsigned short* __restrict__ candG,
    unsigned long long* __restrict__ best) {
  __shared__ float zls[4][D_DIM];
  const int tid = threadIdx.x;
  const int v = tid >> 6, l = tid & 63;
  const int n = blockIdx.x * 4 + v;
  *(float4*)&zls[v][l * 4] = *(const float4*)&z[(size_t)n * D_DIM + l * 4];
  __syncthreads();

  unsigned int cq[4];
  bool full = false;
#pragma unroll
  for (int i = 0; i < 4; ++i) {
    cq[i] = cntG[(size_t)n * 4 + i];
    full |= (cq[i] == 0xFFFFu);
  }
  const float zzn = zz[n];
  unsigned long long key = ~0ull;

  if (!full) {
    const unsigned int o1 = cq[0], o2 = o1 + cq[1], o3 = o2 + cq[2], tot = o3 + cq[3];
    for (unsigned int ci = l; ci < tot; ci += 64) {
      int qq; unsigned int j;
      if (ci >= o3)      { qq = 3; j = ci - o3; }
      else if (ci >= o2) { qq = 2; j = ci - o2; }
      else if (ci >= o1) { qq = 1; j = ci - o1; }
      else               { qq = 0; j = ci; }
      int code = candG[((size_t)n * 4 + qq) * CAPQ + j];
      unsigned long long k2 = exact_key(zls[v], cb, zzn, cc, code);
      key = key < k2 ? key : k2;
    }
  } else {
    for (int code = l; code < K_CB; code += 64) {
      unsigned long long k2 = exact_key(zls[v], cb, zzn, cc, code);
      key = key < k2 ? key : k2;
    }
  }
#pragma unroll
  for (int off = 1; off < 64; off <<= 1) {
    unsigned long long o = __shfl_xor(key, off);
    key = key < o ? key : o;
  }
  if (l == 0) best[n] = key;
}

// ---------------------------------------------------------------------------
// round-1 exact argmin kernel (fallback path when ws too small)
// ---------------------------------------------------------------------------
#define BN  64
#define BKC 128
#define DC  32
#define LDP (DC + 4)
__global__ __launch_bounds__(256) void k_argmin(
    const float* __restrict__ z, const float* __restrict__ cb,
    const float* __restrict__ zz, const float* __restrict__ cc,
    int* __restrict__ out_idx) {
  __shared__ float zs[BN][LDP];
  __shared__ float cs[BKC][LDP];
  __shared__ float red_d[BN][16];
  __shared__ int   red_k[BN][16];
  const int tid = threadIdx.x;
  const int tn = tid & 15, tk = tid >> 4;
  const int n0 = blockIdx.x * BN;
  float zzv[4];
#pragma unroll
  for (int i = 0; i < 4; ++i) zzv[i] = zz[n0 + tn + 16 * i];
  float best[4]; int bidx[4];
#pragma unroll
  for (int i = 0; i < 4; ++i) { best[i] = 3.4e38f; bidx[i] = 0; }
  for (int kt = 0; kt < K_CB / BKC; ++kt) {
    float acc[4][8];
#pragma unroll
    for (int i = 0; i < 4; ++i)
#pragma unroll
      for (int j = 0; j < 8; ++j) acc[i][j] = 0.f;
    for (int ch = 0; ch < D_DIM / DC; ++ch) {
      __syncthreads();
#pragma unroll
      for (int s = 0; s < 2; ++s) {
        int f = tid + 256 * s, r = f >> 3, c4 = f & 7;
        *(float4*)&zs[r][c4 * 4] =
            *(const float4*)&z[(size_t)(n0 + r) * D_DIM + ch * DC + c4 * 4];
      }
#pragma unroll
      for (int s = 0; s < 4; ++s) {
        int f = tid + 256 * s, r = f >> 3, c4 = f & 7;
        *(float4*)&cs[r][c4 * 4] =
            *(const float4*)&cb[(size_t)(kt * BKC + r) * D_DIM + ch * DC + c4 * 4];
      }
      __syncthreads();
#pragma unroll
      for (int qq = 0; qq < DC / 4; ++qq) {
        float4 zr[4], cr[8];
#pragma unroll
        for (int i = 0; i < 4; ++i) zr[i] = *(const float4*)&zs[tn + 16 * i][4 * qq];
#pragma unroll
        for (int j = 0; j < 8; ++j) cr[j] = *(const float4*)&cs[tk + 16 * j][4 * qq];
#pragma unroll
        for (int i = 0; i < 4; ++i)
#pragma unroll
          for (int j = 0; j < 8; ++j) {
            acc[i][j] = fmaf(zr[i].x, cr[j].x, acc[i][j]);
            acc[i][j] = fmaf(zr[i].y, cr[j].y, acc[i][j]);
            acc[i][j] = fmaf(zr[i].z, cr[j].z, acc[i][j]);
            acc[i][j] = fmaf(zr[i].w, cr[j].w, acc[i][j]);
          }
      }
    }
#pragma unroll
    for (int j = 0; j < 8; ++j) {
      const int k = kt * BKC + tk + 16 * j;
      const float cck = cc[k];
#pragma unroll
      for (int i = 0; i < 4; ++i) {
        float t = zzv[i] + cck;
        float dd = fmaf(-2.f, acc[i][j], t);
        if (dd < best[i]) { best[i] = dd; bidx[i] = k; }
      }
    }
  }
#pragma unroll
  for (int i = 0; i < 4; ++i) {
    red_d[tn + 16 * i][tk] = best[i];
    red_k[tn + 16 * i][tk] = bidx[i];
  }
  __syncthreads();
  if (tid < BN) {
    float bd = red_d[tid][0]; int bk = red_k[tid][0];
#pragma unroll
    for (int t2 = 1; t2 < 16; ++t2) {
      float dd = red_d[tid][t2]; int kk = red_k[tid][t2];
      if (dd < bd || (dd == bd && kk < bk)) { bd = dd; bk = kk; }
    }
    out_idx[n0 + tid] = bk;
  }
}

// ---------------------------------------------------------------------------
// gather + straight-through out + loss partials
// ---------------------------------------------------------------------------
template <int MODE>
__global__ __launch_bounds__(256) void k_gather(
    const float* __restrict__ z, const float* __restrict__ cb,
    const void* __restrict__ idx_src, float* __restrict__ out,
    double* __restrict__ accum) {
  const int tid = threadIdx.x;
  const int lane = tid & 63, wv = tid >> 6;
  const int base = blockIdx.x * 64 + wv * 16;
  double lsum = 0.0;
  for (int r = 0; r < 16; ++r) {
    const int n = base + r;
    int k;
    if (MODE == 0) k = ((const int*)idx_src)[n];
    else k = (int)(((const unsigned long long*)idx_src)[n] & 8191ull);
    float4 c4 = *(const float4*)&cb[(size_t)k * D_DIM + lane * 4];
    float4 z4 = *(const float4*)&z[(size_t)n * D_DIM + lane * 4];
    float e0 = c4.x - z4.x, e1 = c4.y - z4.y, e2 = c4.z - z4.z, e3 = c4.w - z4.w;
    lsum += (double)e0 * e0 + (double)e1 * e1 + (double)e2 * e2 + (double)e3 * e3;
    float4 o;
    o.x = z4.x + e0; o.y = z4.y + e1; o.z = z4.z + e2; o.w = z4.w + e3;
    *(float4*)&out[(size_t)n * D_DIM + lane * 4] = o;
    if (lane == 0) out[(size_t)N_PTS * D_DIM + n] = (float)k;
  }
#pragma unroll
  for (int off = 32; off > 0; off >>= 1) lsum += __shfl_down(lsum, off);
  __shared__ double wsum[4];
  if (lane == 0) wsum[wv] = lsum;
  __syncthreads();
  if (tid == 0) atomicAdd(accum, wsum[0] + wsum[1] + wsum[2] + wsum[3]);
}

__global__ void k_loss(const double* __restrict__ accum, float* __restrict__ out) {
  float m = (float)(*accum / (double)((size_t)N_PTS * D_DIM));
  out[(size_t)N_PTS * D_DIM + N_PTS] = BETA * m + m;
}

extern "C" void kernel_launch(void* const* d_in, const int* in_sizes, int n_in,
                              void* d_out, int out_size, void* d_ws, size_t ws_size,
                              hipStream_t stream) {
  const float* z   = (const float*)d_in[0];
  const float* emb = (const float*)d_in[1];
  const float* w   = (const float*)d_in[2];
  const float* b   = (const float*)d_in[3];
  float* out = (float*)d_out;
  char* ws = (char*)d_ws;

  if (ws_size >= WS_NEED) {
    float* cb  = (float*)(ws + OFF_CB);
    f16*   dh  = (f16*)(ws + OFF_DH);
    f16*   uh  = (f16*)(ws + OFF_UH);
    float* cc  = (float*)(ws + OFF_CC);
    float* zz  = (float*)(ws + OFF_ZZ);
    float* dd2 = (float*)(ws + OFF_D2);
    unsigned short* candG = (unsigned short*)(ws + OFF_CAND);
    unsigned int*   cntG  = (unsigned int*)(ws + OFF_CNT);
    unsigned long long* best = (unsigned long long*)(ws + OFF_BEST);
    double* accum = (double*)(ws + OFF_ACC);

    hipMemsetAsync(accum, 0, 8, stream);

    k_codebook<<<K_CB, 256, 0, stream>>>(emb, w, b, cb, cc, dd2, dh);
    k_zz<<<N_PTS / 256, 256, 0, stream>>>(z, zz);
    k_zu<<<(N_PTS * D_DIM) / (8 * 256), 256, 0, stream>>>(z, b, uh);
    k_main<<<256, 512, 0, stream>>>(uh, dh, dd2, cntG, candG);
    k_refine<<<N_PTS / 4, 256, 0, stream>>>(z, cb, zz, cc, cntG, candG, best);
    k_gather<1><<<N_PTS / 64, 256, 0, stream>>>(z, cb, best, out, accum);
    k_loss<<<1, 1, 0, stream>>>(accum, out);
  } else {
    float* ws_f = (float*)d_ws;
    float* cb = ws_f + F_CB_OFF;
    float* cc = ws_f + F_CC_OFF;
    float* zz = ws_f + F_ZZ_OFF;
    int*   idx = (int*)(ws_f + F_IDX_OFF);
    double* accum = (double*)((char*)d_ws + F_ACC_BYTE);
    hipMemsetAsync(accum, 0, sizeof(double), stream);
    k_codebook<<<K_CB, 256, 0, stream>>>(emb, w, b, cb, cc, (float*)nullptr, (f16*)nullptr);
    k_zz<<<N_PTS / 256, 256, 0, stream>>>(z, zz);
    k_argmin<<<N_PTS / BN, 256, 0, stream>>>(z, cb, zz, cc, idx);
    k_gather<0><<<N_PTS / 64, 256, 0, stream>>>(z, cb, idx, out, accum);
    k_loss<<<1, 1, 0, stream>>>(accum, out);
  }
}

// Round 9
// 482.149 us; speedup vs baseline: 163.4453x; 1.3480x over previous
//
#include <hip/hip_runtime.h>

#define N_PTS 32768
#define K_CB  8192
#define D_DIM 256
#define BETA  0.5f

typedef _Float16 f16;
typedef __attribute__((ext_vector_type(8))) _Float16 f16x8;
typedef __attribute__((ext_vector_type(16))) float f32x16;

#define MARGIN  2.5e-4f
#define CAPQ    32
#define DSCALE  4096.0f
#define INV2S   (-4.8828125e-4f)   // -2/4096, exact power of two
#define CBB     16                 // codes per k_codebook block

// ---------------- ws layout (byte offsets) ----------------
#define OFF_CB   ((size_t)0)                                  // f32 [K][D]   8 MB
#define OFF_DH   (OFF_CB   + (size_t)K_CB*D_DIM*4)            // f16 delta*4096 [K][D] 4 MB
#define OFF_UH   (OFF_DH   + (size_t)K_CB*D_DIM*2)            // f16 (z-b) [N][D] 16 MB
#define OFF_CC   (OFF_UH   + (size_t)N_PTS*D_DIM*2)           // f32 ||c||^2 [K]
#define OFF_ZZ   (OFF_CC   + (size_t)K_CB*4)                  // f32 ||z||^2 [N]
#define OFF_D2   (OFF_ZZ   + (size_t)N_PTS*4)                 // f32 ||delta||^2 [K]
#define OFF_CAND (OFF_D2   + (size_t)K_CB*4)                  // u16 [N][4][CAPQ] 8 MB
#define OFF_CNT  (OFF_CAND + (size_t)N_PTS*4*CAPQ*2)          // u32 [N][4]
#define OFF_BEST (OFF_CNT  + (size_t)N_PTS*4*4)               // u64 [N]
#define OFF_ACC  (OFF_BEST + (size_t)N_PTS*8)
#define WS_NEED  (OFF_ACC + 64)

// ---------------- fallback (round-1) ws layout, float offsets ----------------
#define F_CB_OFF   0
#define F_CC_OFF   (K_CB * D_DIM)
#define F_ZZ_OFF   (F_CC_OFF + K_CB)
#define F_IDX_OFF  (F_ZZ_OFF + N_PTS)
#define F_ACC_BYTE ((size_t)(F_IDX_OFF + N_PTS) * 4)

// ---------------------------------------------------------------------------
// k_codebook v2: 16 codes/block, 512 blocks (2/CU).
// cb[k][d] = seq-fma_j(emb[k][j]*W[d][j]) + b[d] — identical op sequence per
// (k,d) as the bit-exact r1/r4 version, now with 16 independent chains/thread.
// W staged per 32-col chunk in LDS (odd stride 37 -> <=2-way bank aliasing);
// es rows broadcast from LDS. cc[k] (order-sensitive) 16 lanes wide; dd2 next 16.
// ---------------------------------------------------------------------------
__global__ __launch_bounds__(256) void k_codebook(
    const float* __restrict__ emb, const float* __restrict__ w,
    const float* __restrict__ bias, float* __restrict__ cb,
    float* __restrict__ cc, float* __restrict__ dd2, f16* __restrict__ dh) {
  __shared__ float esL[CBB][D_DIM];        // 16 KB
  __shared__ float wL[D_DIM][37];          // 37.9 KB (32 cols + odd pad)
  __shared__ float cbL[CBB][D_DIM + 1];    // 16.4 KB (stride 257)
  __shared__ float biasL[D_DIM];           // 1 KB
  const int tid = threadIdx.x;
  const int k0 = blockIdx.x * CBB;

#pragma unroll
  for (int r = 0; r < CBB; ++r) esL[r][tid] = emb[(size_t)(k0 + r) * D_DIM + tid];
  biasL[tid] = bias[tid];
  __syncthreads();

  float acc[CBB];
#pragma unroll
  for (int r = 0; r < CBB; ++r) acc[r] = 0.f;

  const int d = tid;
  for (int ch = 0; ch < 8; ++ch) {
    const int j0 = ch * 32;
    // stage W chunk [256 rows][32 cols]: 2048 float4, coalesced 128B segments
#pragma unroll
    for (int s = 0; s < 8; ++s) {
      int idx = tid + s * 256;
      int row = idx >> 3, c4 = (idx & 7) * 4;
      float4 v = *(const float4*)&w[(size_t)row * D_DIM + j0 + c4];
      wL[row][c4 + 0] = v.x; wL[row][c4 + 1] = v.y;
      wL[row][c4 + 2] = v.z; wL[row][c4 + 3] = v.w;
    }
    __syncthreads();
#pragma unroll
    for (int jj = 0; jj < 32; jj += 4) {
      // per-thread W values (stride-37 scalar reads: <=2-way aliasing, free)
      float w0 = wL[d][jj + 0], w1 = wL[d][jj + 1];
      float w2 = wL[d][jj + 2], w3 = wL[d][jj + 3];
#pragma unroll
      for (int r = 0; r < CBB; ++r) {
        float4 e = *(const float4*)&esL[r][j0 + jj];   // broadcast b128
        acc[r] = fmaf(e.x, w0, acc[r]);
        acc[r] = fmaf(e.y, w1, acc[r]);
        acc[r] = fmaf(e.z, w2, acc[r]);
        acc[r] = fmaf(e.w, w3, acc[r]);
      }
    }
    __syncthreads();
  }

  const float bd = biasL[d];
#pragma unroll
  for (int r = 0; r < CBB; ++r) {
    float a = acc[r] + bd;
    cb[(size_t)(k0 + r) * D_DIM + d] = a;
    cbL[r][d] = a;
    if (dh) dh[(size_t)(k0 + r) * D_DIM + d] = (f16)((a - bd) * DSCALE);
  }
  __syncthreads();
  if (tid < CBB) {
    // cc: sequential-j (order-sensitive, feeds exact refine)
    float s = 0.f;
    for (int j = 0; j < D_DIM; ++j) { float v = cbL[tid][j]; s = fmaf(v, v, s); }
    cc[k0 + tid] = s;
  } else if (tid < 2 * CBB && dd2) {
    int r = tid - CBB;
    float s = 0.f;
    for (int j = 0; j < D_DIM; ++j) { float dl = cbL[r][j] - biasL[j]; s = fmaf(dl, dl, s); }
    dd2[k0 + r] = s;
  }
}

__global__ __launch_bounds__(256) void k_zz(const float* __restrict__ z,
                                            float* __restrict__ zz) {
  const int n = blockIdx.x * 256 + threadIdx.x;
  const float* zr = z + (size_t)n * D_DIM;
  float s = 0.f;
#pragma unroll 8
  for (int q = 0; q < D_DIM / 4; ++q) {
    float4 v = *(const float4*)&zr[q * 4];
    s = fmaf(v.x, v.x, s);
    s = fmaf(v.y, v.y, s);
    s = fmaf(v.z, v.z, s);
    s = fmaf(v.w, v.w, s);
  }
  zz[n] = s;
}

// uh[n][d] = f16(z[n][d] - b[d])
__global__ __launch_bounds__(256) void k_zu(const float* __restrict__ z,
                                            const float* __restrict__ bias,
                                            f16* __restrict__ uh) {
  const size_t i = (size_t)blockIdx.x * 256 + threadIdx.x;  // 8 elems/thread
  const int d0 = (int)((i * 8) & (D_DIM - 1));
  const float4* zp = (const float4*)(z + i * 8);
  float4 a = zp[0], c = zp[1];
  float4 b0 = *(const float4*)&bias[d0];
  float4 b1 = *(const float4*)&bias[d0 + 4];
  f16x8 o = {(f16)(a.x - b0.x), (f16)(a.y - b0.y), (f16)(a.z - b0.z), (f16)(a.w - b0.w),
             (f16)(c.x - b1.x), (f16)(c.y - b1.y), (f16)(c.z - b1.z), (f16)(c.w - b1.w)};
  *(f16x8*)(uh + i * 8) = o;
}

// ---------------------------------------------------------------------------
// k_main: centered f16-MFMA pass. s~(n,k) = -2 u.delta + ||delta||^2
// Grid 256 = 64 row-blocks x 4 code-quarters. Block 512 thr = 8 waves x 64 rows.
// ---------------------------------------------------------------------------
__global__ __launch_bounds__(512, 2) void k_main(
    const f16* __restrict__ uh, const f16* __restrict__ dh,
    const float* __restrict__ dd2,
    unsigned int* __restrict__ cntG, unsigned short* __restrict__ candG) {
  __shared__ __align__(16) char tile[2][16384];
  __shared__ unsigned short candL[512][CAPQ];
  __shared__ unsigned int cntL[512];

  const int tid = threadIdx.x;
  const int w = tid >> 6, l = tid & 63;
  const int lc = l & 31, h = l >> 5;
  const int rb = blockIdx.x >> 2, q = blockIdx.x & 3;
  const int n0 = rb * 512;
  const int lrowA = w * 64 + lc;
  const int lrowB = lrowA + 32;
  const int rowA = n0 + lrowA, rowB = n0 + lrowB;
  const int code0 = q * 2048;

  cntL[tid] = 0;

  // resident u fragments: lane holds k = kc*16 + h*8 + j  (B-operand layout)
  const f16x8* uv = (const f16x8*)uh;
  f16x8 ua[16], ub[16];
#pragma unroll
  for (int kc = 0; kc < 16; ++kc) {
    ua[kc] = uv[(size_t)rowA * 32 + kc * 2 + h];
    ub[kc] = uv[(size_t)rowB * 32 + kc * 2 + h];
  }

  // staging: tile = 1024 16B-slots; slot m -> code m>>5, slot s=m&31;
  // pre-swizzled global source s^(code&7), linear LDS dest
  const f16x8* cv = (const f16x8*)dh;
  const int m0 = tid, m1 = tid + 512;
  const int cl0 = m0 >> 5, s0 = (m0 & 31) ^ (cl0 & 7);
  const int cl1 = m1 >> 5, s1 = (m1 & 31) ^ (cl1 & 7);
  const size_t base0 = (size_t)(code0 + cl0) * 32 + s0;
  const size_t base1 = (size_t)(code0 + cl1) * 32 + s1;

  {
    f16x8 a = cv[base0], b2 = cv[base1];
    *(f16x8*)(tile[0] + m0 * 16) = a;
    *(f16x8*)(tile[0] + m1 * 16) = b2;
  }
  __syncthreads();

  float runA = 3.4e38f, runB = 3.4e38f;
  const float4* d2v = (const float4*)dd2;
  int buf = 0;
  for (int t = 0; t < 64; ++t) {
    f16x8 nx0, nx1;
    if (t < 63) {  // issue next-tile loads early; land after MFMA
      nx0 = cv[base0 + (size_t)(t + 1) * 1024];
      nx1 = cv[base1 + (size_t)(t + 1) * 1024];
    }
    f32x16 accA = {0.f,0.f,0.f,0.f,0.f,0.f,0.f,0.f,0.f,0.f,0.f,0.f,0.f,0.f,0.f,0.f};
    f32x16 accB = {0.f,0.f,0.f,0.f,0.f,0.f,0.f,0.f,0.f,0.f,0.f,0.f,0.f,0.f,0.f,0.f};
    const char* cbase = tile[buf] + lc * 512;
#pragma unroll
    for (int kc = 0; kc < 16; ++kc) {
      f16x8 af = *(const f16x8*)(cbase + (((kc * 2 + h) ^ (lc & 7)) << 4));
      accA = __builtin_amdgcn_mfma_f32_32x32x16_f16(af, ua[kc], accA, 0, 0, 0);
      accB = __builtin_amdgcn_mfma_f32_32x32x16_f16(af, ub[kc], accB, 0, 0, 0);
    }

    // epilogue: s~ = fma(dot, -2^-11, dd2)   (dot = 4096 * u.delta)
    const int tb = code0 + t * 32;
    float sA[16], sB[16];
    float mA = 3.4e38f, mB = 3.4e38f;
#pragma unroll
    for (int r4 = 0; r4 < 4; ++r4) {
      float4 dq = d2v[(tb + 8 * r4 + 4 * h) >> 2];
      sA[4*r4+0] = fmaf(accA[4*r4+0], INV2S, dq.x);
      sA[4*r4+1] = fmaf(accA[4*r4+1], INV2S, dq.y);
      sA[4*r4+2] = fmaf(accA[4*r4+2], INV2S, dq.z);
      sA[4*r4+3] = fmaf(accA[4*r4+3], INV2S, dq.w);
      sB[4*r4+0] = fmaf(accB[4*r4+0], INV2S, dq.x);
      sB[4*r4+1] = fmaf(accB[4*r4+1], INV2S, dq.y);
      sB[4*r4+2] = fmaf(accB[4*r4+2], INV2S, dq.z);
      sB[4*r4+3] = fmaf(accB[4*r4+3], INV2S, dq.w);
      mA = fminf(mA, fminf(fminf(sA[4*r4+0], sA[4*r4+1]), fminf(sA[4*r4+2], sA[4*r4+3])));
      mB = fminf(mB, fminf(fminf(sB[4*r4+0], sB[4*r4+1]), fminf(sB[4*r4+2], sB[4*r4+3])));
    }
    // lanes l and l^32 hold the same rows (different code offsets) -> merge
    mA = fminf(mA, __shfl_xor(mA, 32));
    mB = fminf(mB, __shfl_xor(mB, 32));
    runA = fminf(runA, mA);
    runB = fminf(runB, mB);
    const float thA = runA + MARGIN, thB = runB + MARGIN;
#pragma unroll
    for (int r = 0; r < 16; ++r) {
      const int code = tb + 8 * (r >> 2) + 4 * h + (r & 3);
      if (sA[r] < thA) {
        unsigned int p = atomicAdd(&cntL[lrowA], 1u);
        if (p < CAPQ) candL[lrowA][p] = (unsigned short)code;
      }
      if (sB[r] < thB) {
        unsigned int p = atomicAdd(&cntL[lrowB], 1u);
        if (p < CAPQ) candL[lrowB][p] = (unsigned short)code;
      }
    }
    if (t < 63) {
      *(f16x8*)(tile[buf ^ 1] + m0 * 16) = nx0;
      *(f16x8*)(tile[buf ^ 1] + m1 * 16) = nx1;
    }
    __syncthreads();
    buf ^= 1;
  }

  // writeout: thread tid owns row n0+tid
  unsigned int c = cntL[tid];
  unsigned int cw = (c > CAPQ) ? 0xFFFFu : c;
  cntG[((size_t)(n0 + tid)) * 4 + q] = cw;
  unsigned int nc = (cw == 0xFFFFu) ? 0u : cw;
  for (unsigned int j = 0; j < nc; ++j)
    candG[(((size_t)(n0 + tid)) * 4 + q) * CAPQ + j] = candL[tid][j];
}

// exact fp32 distance, bit-replicating the round-1 (reference-matching) formula
__device__ inline unsigned long long exact_key(const float* __restrict__ zr,
                                               const float* __restrict__ cb,
                                               float zzn, const float* __restrict__ cc,
                                               int code) {
  float acc = 0.f;
  const float4* cr = (const float4*)&cb[(size_t)code * D_DIM];
  const float4* z4p = (const float4*)zr;
#pragma unroll 8
  for (int u = 0; u < D_DIM / 4; ++u) {
    float4 c4 = cr[u], z4 = z4p[u];
    acc = fmaf(z4.x, c4.x, acc);
    acc = fmaf(z4.y, c4.y, acc);
    acc = fmaf(z4.z, c4.z, acc);
    acc = fmaf(z4.w, c4.w, acc);
  }
  float t = zzn + cc[code];
  float dd = fmaf(-2.f, acc, t);
  return (((unsigned long long)__float_as_uint(dd)) << 32) | (unsigned int)code;
}

// one wave per row; refine candidate lists (or full-scan on sentinel)
__global__ __launch_bounds__(256) void k_refine(
    const float* __restrict__ z, const float* __restrict__ cb,
    const float* __restrict__ zz, const float* __restrict__ cc,
    const unsigned int* __restrict__ cntG, const unsigned short* __restrict__ candG,
    unsigned long long* __restrict__ best) {
  __shared__ float zls[4][D_DIM];
  const int tid = threadIdx.x;
  const int v = tid >> 6, l = tid & 63;
  const int n = blockIdx.x * 4 + v;
  *(float4*)&zls[v][l * 4] = *(const float4*)&z[(size_t)n * D_DIM + l * 4];
  __syncthreads();

  unsigned int cq[4];
  bool full = false;
#pragma unroll
  for (int i = 0; i < 4; ++i) {
    cq[i] = cntG[(size_t)n * 4 + i];
    full |= (cq[i] == 0xFFFFu);
  }
  const float zzn = zz[n];
  unsigned long long key = ~0ull;

  if (!full) {
    const unsigned int o1 = cq[0], o2 = o1 + cq[1], o3 = o2 + cq[2], tot = o3 + cq[3];
    for (unsigned int ci = l; ci < tot; ci += 64) {
      int qq; unsigned int j;
      if (ci >= o3)      { qq = 3; j = ci - o3; }
      else if (ci >= o2) { qq = 2; j = ci - o2; }
      else if (ci >= o1) { qq = 1; j = ci - o1; }
      else               { qq = 0; j = ci; }
      int code = candG[((size_t)n * 4 + qq) * CAPQ + j];
      unsigned long long k2 = exact_key(zls[v], cb, zzn, cc, code);
      key = key < k2 ? key : k2;
    }
  } else {
    for (int code = l; code < K_CB; code += 64) {
      unsigned long long k2 = exact_key(zls[v], cb, zzn, cc, code);
      key = key < k2 ? key : k2;
    }
  }
#pragma unroll
  for (int off = 1; off < 64; off <<= 1) {
    unsigned long long o = __shfl_xor(key, off);
    key = key < o ? key : o;
  }
  if (l == 0) best[n] = key;
}

// ---------------------------------------------------------------------------
// round-1 exact argmin kernel (fallback path when ws too small)
// ---------------------------------------------------------------------------
#define BN  64
#define BKC 128
#define DC  32
#define LDP (DC + 4)
__global__ __launch_bounds__(256) void k_argmin(
    const float* __restrict__ z, const float* __restrict__ cb,
    const float* __restrict__ zz, const float* __restrict__ cc,
    int* __restrict__ out_idx) {
  __shared__ float zs[BN][LDP];
  __shared__ float cs[BKC][LDP];
  __shared__ float red_d[BN][16];
  __shared__ int   red_k[BN][16];
  const int tid = threadIdx.x;
  const int tn = tid & 15, tk = tid >> 4;
  const int n0 = blockIdx.x * BN;
  float zzv[4];
#pragma unroll
  for (int i = 0; i < 4; ++i) zzv[i] = zz[n0 + tn + 16 * i];
  float best[4]; int bidx[4];
#pragma unroll
  for (int i = 0; i < 4; ++i) { best[i] = 3.4e38f; bidx[i] = 0; }
  for (int kt = 0; kt < K_CB / BKC; ++kt) {
    float acc[4][8];
#pragma unroll
    for (int i = 0; i < 4; ++i)
#pragma unroll
      for (int j = 0; j < 8; ++j) acc[i][j] = 0.f;
    for (int ch = 0; ch < D_DIM / DC; ++ch) {
      __syncthreads();
#pragma unroll
      for (int s = 0; s < 2; ++s) {
        int f = tid + 256 * s, r = f >> 3, c4 = f & 7;
        *(float4*)&zs[r][c4 * 4] =
            *(const float4*)&z[(size_t)(n0 + r) * D_DIM + ch * DC + c4 * 4];
      }
#pragma unroll
      for (int s = 0; s < 4; ++s) {
        int f = tid + 256 * s, r = f >> 3, c4 = f & 7;
        *(float4*)&cs[r][c4 * 4] =
            *(const float4*)&cb[(size_t)(kt * BKC + r) * D_DIM + ch * DC + c4 * 4];
      }
      __syncthreads();
#pragma unroll
      for (int qq = 0; qq < DC / 4; ++qq) {
        float4 zr[4], cr[8];
#pragma unroll
        for (int i = 0; i < 4; ++i) zr[i] = *(const float4*)&zs[tn + 16 * i][4 * qq];
#pragma unroll
        for (int j = 0; j < 8; ++j) cr[j] = *(const float4*)&cs[tk + 16 * j][4 * qq];
#pragma unroll
        for (int i = 0; i < 4; ++i)
#pragma unroll
          for (int j = 0; j < 8; ++j) {
            acc[i][j] = fmaf(zr[i].x, cr[j].x, acc[i][j]);
            acc[i][j] = fmaf(zr[i].y, cr[j].y, acc[i][j]);
            acc[i][j] = fmaf(zr[i].z, cr[j].z, acc[i][j]);
            acc[i][j] = fmaf(zr[i].w, cr[j].w, acc[i][j]);
          }
      }
    }
#pragma unroll
    for (int j = 0; j < 8; ++j) {
      const int k = kt * BKC + tk + 16 * j;
      const float cck = cc[k];
#pragma unroll
      for (int i = 0; i < 4; ++i) {
        float t = zzv[i] + cck;
        float dd = fmaf(-2.f, acc[i][j], t);
        if (dd < best[i]) { best[i] = dd; bidx[i] = k; }
      }
    }
  }
#pragma unroll
  for (int i = 0; i < 4; ++i) {
    red_d[tn + 16 * i][tk] = best[i];
    red_k[tn + 16 * i][tk] = bidx[i];
  }
  __syncthreads();
  if (tid < BN) {
    float bd = red_d[tid][0]; int bk = red_k[tid][0];
#pragma unroll
    for (int t2 = 1; t2 < 16; ++t2) {
      float dd = red_d[tid][t2]; int kk = red_k[tid][t2];
      if (dd < bd || (dd == bd && kk < bk)) { bd = dd; bk = kk; }
    }
    out_idx[n0 + tid] = bk;
  }
}

// ---------------------------------------------------------------------------
// gather + straight-through out + loss partials
// ---------------------------------------------------------------------------
template <int MODE>
__global__ __launch_bounds__(256) void k_gather(
    const float* __restrict__ z, const float* __restrict__ cb,
    const void* __restrict__ idx_src, float* __restrict__ out,
    double* __restrict__ accum) {
  const int tid = threadIdx.x;
  const int lane = tid & 63, wv = tid >> 6;
  const int base = blockIdx.x * 64 + wv * 16;
  double lsum = 0.0;
  for (int r = 0; r < 16; ++r) {
    const int n = base + r;
    int k;
    if (MODE == 0) k = ((const int*)idx_src)[n];
    else k = (int)(((const unsigned long long*)idx_src)[n] & 8191ull);
    float4 c4 = *(const float4*)&cb[(size_t)k * D_DIM + lane * 4];
    float4 z4 = *(const float4*)&z[(size_t)n * D_DIM + lane * 4];
    float e0 = c4.x - z4.x, e1 = c4.y - z4.y, e2 = c4.z - z4.z, e3 = c4.w - z4.w;
    lsum += (double)e0 * e0 + (double)e1 * e1 + (double)e2 * e2 + (double)e3 * e3;
    float4 o;
    o.x = z4.x + e0; o.y = z4.y + e1; o.z = z4.z + e2; o.w = z4.w + e3;
    *(float4*)&out[(size_t)n * D_DIM + lane * 4] = o;
    if (lane == 0) out[(size_t)N_PTS * D_DIM + n] = (float)k;
  }
#pragma unroll
  for (int off = 32; off > 0; off >>= 1) lsum += __shfl_down(lsum, off);
  __shared__ double wsum[4];
  if (lane == 0) wsum[wv] = lsum;
  __syncthreads();
  if (tid == 0) atomicAdd(accum, wsum[0] + wsum[1] + wsum[2] + wsum[3]);
}

__global__ void k_loss(const double* __restrict__ accum, float* __restrict__ out) {
  float m = (float)(*accum / (double)((size_t)N_PTS * D_DIM));
  out[(size_t)N_PTS * D_DIM + N_PTS] = BETA * m + m;
}

extern "C" void kernel_launch(void* const* d_in, const int* in_sizes, int n_in,
                              void* d_out, int out_size, void* d_ws, size_t ws_size,
                              hipStream_t stream) {
  const float* z   = (const float*)d_in[0];
  const float* emb = (const float*)d_in[1];
  const float* w   = (const float*)d_in[2];
  const float* b   = (const float*)d_in[3];
  float* out = (float*)d_out;
  char* ws = (char*)d_ws;

  if (ws_size >= WS_NEED) {
    float* cb  = (float*)(ws + OFF_CB);
    f16*   dh  = (f16*)(ws + OFF_DH);
    f16*   uh  = (f16*)(ws + OFF_UH);
    float* cc  = (float*)(ws + OFF_CC);
    float* zz  = (float*)(ws + OFF_ZZ);
    float* dd2 = (float*)(ws + OFF_D2);
    unsigned short* candG = (unsigned short*)(ws + OFF_CAND);
    unsigned int*   cntG  = (unsigned int*)(ws + OFF_CNT);
    unsigned long long* best = (unsigned long long*)(ws + OFF_BEST);
    double* accum = (double*)(ws + OFF_ACC);

    hipMemsetAsync(accum, 0, 8, stream);

    k_codebook<<<K_CB / CBB, 256, 0, stream>>>(emb, w, b, cb, cc, dd2, dh);
    k_zz<<<N_PTS / 256, 256, 0, stream>>>(z, zz);
    k_zu<<<(N_PTS * D_DIM) / (8 * 256), 256, 0, stream>>>(z, b, uh);
    k_main<<<256, 512, 0, stream>>>(uh, dh, dd2, cntG, candG);
    k_refine<<<N_PTS / 4, 256, 0, stream>>>(z, cb, zz, cc, cntG, candG, best);
    k_gather<1><<<N_PTS / 64, 256, 0, stream>>>(z, cb, best, out, accum);
    k_loss<<<1, 1, 0, stream>>>(accum, out);
  } else {
    float* ws_f = (float*)d_ws;
    float* cb = ws_f + F_CB_OFF;
    float* cc = ws_f + F_CC_OFF;
    float* zz = ws_f + F_ZZ_OFF;
    int*   idx = (int*)(ws_f + F_IDX_OFF);
    double* accum = (double*)((char*)d_ws + F_ACC_BYTE);
    hipMemsetAsync(accum, 0, sizeof(double), stream);
    k_codebook<<<K_CB / CBB, 256, 0, stream>>>(emb, w, b, cb, cc, (float*)nullptr, (f16*)nullptr);
    k_zz<<<N_PTS / 256, 256, 0, stream>>>(z, zz);
    k_argmin<<<N_PTS / BN, 256, 0, stream>>>(z, cb, zz, cc, idx);
    k_gather<0><<<N_PTS / 64, 256, 0, stream>>>(z, cb, idx, out, accum);
    k_loss<<<1, 1, 0, stream>>>(accum, out);
  }
}